// Round 8
// baseline (130.241 us; speedup 1.0000x reference)
//
#include <hip/hip_runtime.h>
#include <hip/hip_bf16.h>

// Chamfer distance: B=4, S=4, N=M=4096, D=3, fp32 in/out.
// out[s*B + b] = mean_n min_m d2(n,m) + mean_m min_n d2(n,m)
//
// R8: MFMA path. R7 hit the fp32 VALU roofline (~46us = measured pk_fma@8cyc
// floor; gfx950 has no 2x packed-fp32 datapath). Reformulate as bf16 MFMA:
//   G[n,m] = q.r - |q|^2/2 - |r|^2/2 = -d2/2   (ONE matrix serves both dirs:
//   dist1[n] = max(-2*rowmax G, 0), dist2[m] = max(-2*colmax G, 0))
// Precision: fp32 -> bf16 hi+lo split; K=16 slots carry all hi/lo cross
// products AND the folded norm terms:
//   A[n] = [xh,xl,xh,xl, yh,yl,yh,yl, zh,zl,zh,zl, 1,1, nh,nl]  (n* = -x2/2)
//   B[m] = [xh,xh,xl,xl, yh,yh,yl,yl, zh,zh,zl,zl, nh,nl, 1,1]  (n* = -y2/2)
// slot-wise dot = q.r (exact, incl ql*rl) - x2/2 - y2/2; err ~1e-4 << 1.48e-3.
// One v_mfma_f32_32x32x16_bf16 per 32x32 tile (single K step).
// C/D layout (m74/m101): col=lane&31, row=(reg&3)+8*(reg>>2)+4*(lane>>5).
// Note: output is symmetric under G<->G^T (row+col terms summed), so a
// transposed layout assumption cannot corrupt the result.

constexpr int BB = 4, SS = 4, NPTS = 4096, PAIRS = 16;
constexpr int BANDS = 32;              // 128 rows per workgroup band
constexpr int TPB = 256;               // 4 waves; wave w owns rows band*128+w*32..+32

typedef __bf16 bf16x8 __attribute__((ext_vector_type(8)));
typedef float f32x16 __attribute__((ext_vector_type(16)));

constexpr size_t APACK_BYTES = (size_t)PAIRS * NPTS * 16 * 2;   // 2 MB
constexpr size_t BPACK_OFF   = APACK_BYTES;
constexpr size_t COLP_OFF    = 2 * APACK_BYTES;                 // 4 MB
constexpr size_t COLP_BYTES  = (size_t)PAIRS * BANDS * NPTS * 4; // 8 MB
constexpr size_t WS_NEED_MFMA = COLP_OFF + COLP_BYTES;

// ---- pack: build A/B K=16 bf16 rows ----
__global__ void pack_kernel(const float* __restrict__ outp,
                            const float* __restrict__ tgtp,
                            __bf16* __restrict__ apack,
                            __bf16* __restrict__ bpack) {
  const int idx = blockIdx.x * TPB + threadIdx.x;  // 0..131071
  const int which = idx >> 16;                      // 0 = A (queries), 1 = B (refs)
  const int pn = idx & 65535;                       // pair*4096 + n
  const float* p = (which ? tgtp : outp) + (size_t)pn * 3;
  const float x = p[0], y = p[1], z = p[2];
  const float n2 = -0.5f * (x * x + y * y + z * z);
  const __bf16 xh = (__bf16)x, yh = (__bf16)y, zh = (__bf16)z, nh = (__bf16)n2;
  const __bf16 xl = (__bf16)(x - (float)xh);
  const __bf16 yl = (__bf16)(y - (float)yh);
  const __bf16 zl = (__bf16)(z - (float)zh);
  const __bf16 nl = (__bf16)(n2 - (float)nh);
  const __bf16 one = (__bf16)1.0f;
  union { __bf16 h[16]; uint4 q[2]; } u;
  if (which == 0) {
    u.h[0]=xh; u.h[1]=xl; u.h[2]=xh; u.h[3]=xl;
    u.h[4]=yh; u.h[5]=yl; u.h[6]=yh; u.h[7]=yl;
    u.h[8]=zh; u.h[9]=zl; u.h[10]=zh; u.h[11]=zl;
    u.h[12]=one; u.h[13]=one; u.h[14]=nh; u.h[15]=nl;
    uint4* dst = (uint4*)(apack + (size_t)pn * 16);
    dst[0] = u.q[0]; dst[1] = u.q[1];
  } else {
    u.h[0]=xh; u.h[1]=xh; u.h[2]=xl; u.h[3]=xl;
    u.h[4]=yh; u.h[5]=yh; u.h[6]=yl; u.h[7]=yl;
    u.h[8]=zh; u.h[9]=zh; u.h[10]=zl; u.h[11]=zl;
    u.h[12]=nh; u.h[13]=nl; u.h[14]=one; u.h[15]=one;
    uint4* dst = (uint4*)(bpack + (size_t)pn * 16);
    dst[0] = u.q[0]; dst[1] = u.q[1];
  }
}

// ---- main: per (band,pair) workgroup; wave w = rows band*128+w*32..+32 ----
__global__ __launch_bounds__(TPB, 2)
void chamfer_mfma_kernel(const __bf16* __restrict__ apack,
                         const __bf16* __restrict__ bpack,
                         float* __restrict__ colp,
                         float* __restrict__ out) {
  const int t = threadIdx.x, l = t & 63, w = t >> 6;
  const int band = blockIdx.x, pair = blockIdx.y;
  const int c32 = l & 31, h = l >> 5;

  __shared__ float cpart[4][1024];   // per-wave col partials for one 1024-col chunk

  // A fragment (persistent): A[m=lane&31][k = 8*(lane>>5)+j]
  const int row = band * 128 + w * 32 + c32;
  const bf16x8 afrag =
      *(const bf16x8*)(apack + ((size_t)pair * NPTS + row) * 16 + h * 8);

  f32x16 zacc;
  #pragma unroll
  for (int i = 0; i < 16; ++i) zacc[i] = 0.0f;

  float rowM[16];
  #pragma unroll
  for (int i = 0; i < 16; ++i) rowM[i] = -3.0e38f;

  const __bf16* bbase = bpack + (size_t)pair * NPTS * 16;

  for (int chunk = 0; chunk < 4; ++chunk) {
    __syncthreads();                 // cpart free for reuse
    #pragma unroll 2
    for (int ct = 0; ct < 32; ++ct) {
      const int col = chunk * 1024 + ct * 32 + c32;
      const bf16x8 bfrag = *(const bf16x8*)(bbase + (size_t)col * 16 + h * 8);
      const f32x16 acc =
          __builtin_amdgcn_mfma_f32_32x32x16_bf16(afrag, bfrag, zacc, 0, 0, 0);
      #pragma unroll
      for (int i = 0; i < 16; ++i) rowM[i] = fmaxf(rowM[i], acc[i]);
      // col-max: explicit tree over the 16 regs (rows in this lane)...
      float m0 = fmaxf(acc[0], acc[1]),  m1 = fmaxf(acc[2], acc[3]);
      float m2 = fmaxf(acc[4], acc[5]),  m3 = fmaxf(acc[6], acc[7]);
      float m4 = fmaxf(acc[8], acc[9]),  m5 = fmaxf(acc[10], acc[11]);
      float m6 = fmaxf(acc[12], acc[13]), m7 = fmaxf(acc[14], acc[15]);
      float cm = fmaxf(fmaxf(fmaxf(m0, m1), fmaxf(m2, m3)),
                       fmaxf(fmaxf(m4, m5), fmaxf(m6, m7)));
      // ...then the other 16 rows live in lane^32
      cm = fmaxf(cm, __shfl_xor(cm, 32, 64));
      cpart[w][ct * 32 + c32] = cm;  // both halves write same value/addr
    }
    __syncthreads();                 // cpart complete
    // merge 4 waves -> 1024 col partials, write to ws (coalesced float4)
    const int c0 = t * 4;
    float4 v;
    v.x = fmaxf(fmaxf(cpart[0][c0+0], cpart[1][c0+0]), fmaxf(cpart[2][c0+0], cpart[3][c0+0]));
    v.y = fmaxf(fmaxf(cpart[0][c0+1], cpart[1][c0+1]), fmaxf(cpart[2][c0+1], cpart[3][c0+1]));
    v.z = fmaxf(fmaxf(cpart[0][c0+2], cpart[1][c0+2]), fmaxf(cpart[2][c0+2], cpart[3][c0+2]));
    v.w = fmaxf(fmaxf(cpart[0][c0+3], cpart[1][c0+3]), fmaxf(cpart[2][c0+3], cpart[3][c0+3]));
    *(float4*)(colp + ((size_t)(pair * BANDS + band)) * NPTS + chunk * 1024 + c0) = v;
  }

  // ---- row direction: butterfly max over lanes 0..31 (cols), all 16 regs
  #pragma unroll
  for (int m = 1; m < 32; m <<= 1) {
    #pragma unroll
    for (int i = 0; i < 16; ++i)
      rowM[i] = fmaxf(rowM[i], __shfl_xor(rowM[i], m, 64));
  }
  float s = 0.0f;
  #pragma unroll
  for (int i = 0; i < 16; ++i) s += fmaxf(-2.0f * rowM[i], 0.0f);  // 16 rows (this half)
  s += __shfl_xor(s, 32, 64);        // + other half's 16 rows
  if (l == 0) {
    const int b = pair >> 2, sx = pair & 3;     // pair = b*S + s
    atomicAdd(&out[sx * BB + b], s * (1.0f / NPTS));
  }
}

// ---- final: reduce col partials across the 32 bands ----
__global__ void colred_kernel(const float* __restrict__ colp,
                              float* __restrict__ out) {
  const int t = threadIdx.x;
  const int col = blockIdx.x * TPB + t;
  const int pair = blockIdx.y;
  const float* base = colp + (size_t)pair * BANDS * NPTS + col;
  float g = -3.0e38f;
  #pragma unroll 4
  for (int bnd = 0; bnd < BANDS; ++bnd) g = fmaxf(g, base[(size_t)bnd * NPTS]);
  float d = fmaxf(-2.0f * g, 0.0f);
  #pragma unroll
  for (int off = 1; off < 64; off <<= 1) d += __shfl_xor(d, off, 64);
  __shared__ float red[4];
  if ((t & 63) == 0) red[t >> 6] = d;
  __syncthreads();
  if (t == 0) {
    const float ssum = red[0] + red[1] + red[2] + red[3];
    const int b = pair >> 2, sx = pair & 3;
    atomicAdd(&out[sx * BB + b], ssum * (1.0f / NPTS));
  }
}

// ---- R7 fallback (fp32 VALU, pk_fma) if ws is too small ----
typedef float v2f __attribute__((ext_vector_type(2)));
#define PK_FMA_ZW(g, q, rzw)                                              \
  asm("v_pk_fma_f32 %0, %1, %2, %2 op_sel:[0,0,1] op_sel_hi:[1,0,1]"      \
      : "=v"(g) : "v"(q), "v"(rzw))
#define PK_FMA_Y(g, q, rxy)                                               \
  asm("v_pk_fma_f32 %0, %1, %2, %0 op_sel:[0,1,0] op_sel_hi:[1,1,1]"      \
      : "+v"(g) : "v"(q), "v"(rxy))
#define PK_FMA_X(g, q, rxy)                                               \
  asm("v_pk_fma_f32 %0, %1, %2, %0 op_sel:[0,0,0] op_sel_hi:[1,0,1]"      \
      : "+v"(g) : "v"(q), "v"(rxy))

__global__ __launch_bounds__(1024, 4)
void chamfer_pk3_kernel(const float* __restrict__ out_pts,
                        const float* __restrict__ tgt_pts,
                        float* __restrict__ out) {
  const int t = threadIdx.x, l = t & 63, wid = t >> 6;
  const int qtile = blockIdx.x, pair = blockIdx.y, dir = blockIdx.z;
  const float* qbase = (dir == 0 ? out_pts : tgt_pts) + (size_t)pair * NPTS * 3;
  const float* rbase = (dir == 0 ? tgt_pts : out_pts) + (size_t)pair * NPTS * 3;
  __shared__ float4 sref[NPTS];
  #pragma unroll
  for (int k = 0; k < 4; ++k) {
    const int i = t + k * 1024;
    const float rx = rbase[3*i], ry = rbase[3*i+1], rz = rbase[3*i+2];
    sref[i] = make_float4(rx, ry, rz, -0.5f * (rx*rx + ry*ry + rz*rz));
  }
  v2f qx[4], qy[4], qz[4];
  #pragma unroll
  for (int p = 0; p < 4; ++p) {
    const int q0 = qtile * 512 + (2*p)*64 + l, q1 = q0 + 64;
    qx[p] = v2f{qbase[3*q0],   qbase[3*q1]};
    qy[p] = v2f{qbase[3*q0+1], qbase[3*q1+1]};
    qz[p] = v2f{qbase[3*q0+2], qbase[3*q1+2]};
  }
  float acc[8];
  #pragma unroll
  for (int j = 0; j < 8; ++j) acc[j] = -3.0e38f;
  __syncthreads();
  const int base = wid * 256;
  #pragma unroll 2
  for (int r = 0; r < 256; r += 2) {
    const float4 rf0 = sref[base + r], rf1 = sref[base + r + 1];
    v2f rxy0{rf0.x, rf0.y}, rzw0{rf0.z, rf0.w};
    v2f rxy1{rf1.x, rf1.y}, rzw1{rf1.z, rf1.w};
    #pragma unroll
    for (int p = 0; p < 4; ++p) {
      v2f g0, g1;
      PK_FMA_ZW(g0, qz[p], rzw0); PK_FMA_Y(g0, qy[p], rxy0); PK_FMA_X(g0, qx[p], rxy0);
      PK_FMA_ZW(g1, qz[p], rzw1); PK_FMA_Y(g1, qy[p], rxy1); PK_FMA_X(g1, qx[p], rxy1);
      acc[2*p]   = fmaxf(fmaxf(acc[2*p],   g0.x), g1.x);
      acc[2*p+1] = fmaxf(fmaxf(acc[2*p+1], g0.y), g1.y);
    }
  }
  __syncthreads();
  float* Sf = reinterpret_cast<float*>(sref);
  #pragma unroll
  for (int j = 0; j < 8; ++j) Sf[wid * 512 + j * 64 + l] = acc[j];
  __syncthreads();
  if (t < 512) {
    float g = Sf[t];
    #pragma unroll
    for (int w2 = 1; w2 < 16; ++w2) g = fmaxf(g, Sf[w2 * 512 + t]);
    const int j = t >> 6, p = j >> 1, hh = j & 1;
    const float x2 = qx[p][hh]*qx[p][hh] + qy[p][hh]*qy[p][hh] + qz[p][hh]*qz[p][hh];
    float d = fmaxf(fmaf(-2.0f, g, x2), 0.0f);
    #pragma unroll
    for (int off = 1; off < 64; off <<= 1) d += __shfl_xor(d, off, 64);
    if (l == 0) Sf[16 * 512 + (t >> 6)] = d;
  }
  __syncthreads();
  if (t == 0) {
    float ssum = 0.0f;
    #pragma unroll
    for (int w2 = 0; w2 < 8; ++w2) ssum += Sf[16 * 512 + w2];
    const int b = pair >> 2, sx = pair & 3;
    atomicAdd(&out[sx * BB + b], ssum * (1.0f / NPTS));
  }
}

extern "C" void kernel_launch(void* const* d_in, const int* in_sizes, int n_in,
                              void* d_out, int out_size, void* d_ws, size_t ws_size,
                              hipStream_t stream) {
  const float* out_pts = (const float*)d_in[0];
  const float* tgt_pts = (const float*)d_in[1];
  float* out = (float*)d_out;

  hipMemsetAsync(out, 0, out_size * sizeof(float), stream);
  if (ws_size >= WS_NEED_MFMA) {
    __bf16* apack = (__bf16*)((char*)d_ws);
    __bf16* bpack = (__bf16*)((char*)d_ws + BPACK_OFF);
    float*  colp  = (float*)((char*)d_ws + COLP_OFF);
    pack_kernel<<<512, TPB, 0, stream>>>(out_pts, tgt_pts, apack, bpack);
    chamfer_mfma_kernel<<<dim3(BANDS, PAIRS), TPB, 0, stream>>>(apack, bpack, colp, out);
    colred_kernel<<<dim3(NPTS / TPB, PAIRS), TPB, 0, stream>>>(colp, out);
  } else {
    chamfer_pk3_kernel<<<dim3(8, PAIRS, 2), 1024, 0, stream>>>(out_pts, tgt_pts, out);
  }
}